// Round 6
// baseline (1519.158 us; speedup 1.0000x reference)
//
#include <hip/hip_runtime.h>

// 2-D bucketed counting sort + fully-LDS accumulation.
// R3-R5 learning: k_accum was bound by 25.6M divergent global gathers of
// charges[src] (~45 G random 64B lines/s device ceiling) — occupancy/banks/
// NT/MLP all neutral. R6: sort tuples by (dest_bucket, src_bucket), both
// 4096 atoms; k_accum stages the src charge slice in LDS (64KB) next to the
// 64KB dest accumulator -> the gather becomes an LDS read. No random global
// accesses left in the whole pipeline.

#define DB_LOG   12
#define D_B      4096          // dest bucket atoms (64 KB LDS acc, 4 ch)
#define SB_LOG   12
#define S_B      4096          // src bucket atoms (64 KB LDS stage)
#define KEYS_MAX 2560          // LDS histogram/cursor arrays (10 KB)
#define NBLK_S   192           // hist/scatter blocks (write-line set <= L2)
#define SBLOCK   512
#define GPB      3             // src groups per accum block

static __device__ __forceinline__ unsigned long long nt_u64(const void* p) {
    return __builtin_nontemporal_load((const unsigned long long*)p);
}
static __device__ __forceinline__ float nt_f32(const float* p) {
    return __builtin_nontemporal_load(p);
}
static __device__ __forceinline__ void nt_store(float* p, float v) {
    __builtin_nontemporal_store(v, p);
}

// ---- K1: per-block histogram over (dest,src) keys -----------------------
__global__ __launch_bounds__(SBLOCK) void k_hist(
    const int2* __restrict__ nbr, int* __restrict__ tmp,
    int n_edges, int nkeys, int ns)
{
    __shared__ int h[KEYS_MAX];
    for (int i = threadIdx.x; i < nkeys; i += blockDim.x) h[i] = 0;
    __syncthreads();
    int per = (n_edges + gridDim.x - 1) / gridDim.x;
    int lo = blockIdx.x * per;
    int hi = min(lo + per, n_edges);
    #pragma unroll 4
    for (int e = lo + threadIdx.x; e < hi; e += blockDim.x) {
        unsigned long long v = nt_u64(&nbr[e]);
        int ix = (int)(v & 0xffffffffu);
        int iy = (int)(v >> 32);
        atomicAdd(&h[(ix >> DB_LOG) * ns + (iy >> SB_LOG)], 1);
        atomicAdd(&h[(iy >> DB_LOG) * ns + (ix >> SB_LOG)], 1);
    }
    __syncthreads();
    int* row = tmp + (size_t)blockIdx.x * nkeys;     // [blk][key], coalesced
    for (int i = threadIdx.x; i < nkeys; i += blockDim.x) row[i] = h[i];
}

// ---- K2: per-key exclusive scan over the NBLK_S blocks ------------------
__global__ __launch_bounds__(256) void k_rowscan(
    const int* __restrict__ tmp, int* __restrict__ offs,
    int* __restrict__ totals, int nkeys)
{
    __shared__ int a[256];
    int key = blockIdx.x, t = threadIdx.x;
    int v = (t < NBLK_S) ? tmp[(size_t)t * nkeys + key] : 0;
    a[t] = v;
    __syncthreads();
    for (int off = 1; off < 256; off <<= 1) {
        int x = (t >= off) ? a[t - off] : 0;
        __syncthreads();
        a[t] += x;
        __syncthreads();
    }
    if (t < NBLK_S) offs[(size_t)t * nkeys + key] = a[t] - v;  // excl within key
    if (t == 255) totals[key] = a[t];
}

// ---- K3: exclusive scan of key totals (one block, 3 keys/thread) --------
__global__ __launch_bounds__(1024) void k_bases(
    const int* __restrict__ totals, int* __restrict__ key_base, int nkeys)
{
    __shared__ int a[1024];
    int t = threadIdx.x;
    int i0 = 3 * t;
    int s0 = (i0     < nkeys) ? totals[i0]     : 0;
    int s1 = (i0 + 1 < nkeys) ? totals[i0 + 1] : 0;
    int s2 = (i0 + 2 < nkeys) ? totals[i0 + 2] : 0;
    int local = s0 + s1 + s2;
    a[t] = local;
    __syncthreads();
    for (int off = 1; off < 1024; off <<= 1) {
        int x = (t >= off) ? a[t - off] : 0;
        __syncthreads();
        a[t] += x;
        __syncthreads();
    }
    int base = a[t] - local;    // exclusive
    if (i0     < nkeys) key_base[i0]     = base;
    if (i0 + 1 < nkeys) key_base[i0 + 1] = base + s0;
    if (i0 + 2 < nkeys) key_base[i0 + 2] = base + s0 + s1;
}

// ---- K4: offs[i] += key_base[i % nkeys]  (layout [blk][key]) ------------
__global__ void k_addbase(int* __restrict__ offs, const int* __restrict__ key_base,
                          int n, int nkeys)
{
    int i = blockIdx.x * blockDim.x + threadIdx.x;
    if (i < n) offs[i] += key_base[i % nkeys];
}

// ---- K5: counting-sort scatter of 8B tuples -----------------------------
__global__ __launch_bounds__(SBLOCK) void k_scatter(
    const int2* __restrict__ nbr, const float* __restrict__ dist,
    const int* __restrict__ offs, uint2* __restrict__ tuples,
    int n_edges, int nkeys, int ns)
{
    __shared__ int cur[KEYS_MAX];
    const int* row = offs + (size_t)blockIdx.x * nkeys;
    for (int i = threadIdx.x; i < nkeys; i += blockDim.x) cur[i] = row[i];
    __syncthreads();
    int per = (n_edges + gridDim.x - 1) / gridDim.x;
    int lo = blockIdx.x * per;
    int hi = min(lo + per, n_edges);
    #pragma unroll 4
    for (int e = lo + threadIdx.x; e < hi; e += blockDim.x) {
        unsigned long long v = nt_u64(&nbr[e]);
        int ix = (int)(v & 0xffffffffu);
        int iy = (int)(v >> 32);
        float w = 0.5f / nt_f32(&dist[e]);
        unsigned wb = __float_as_uint(w);
        int k1 = (ix >> DB_LOG) * ns + (iy >> SB_LOG);
        int p1 = atomicAdd(&cur[k1], 1);
        tuples[p1] = make_uint2((unsigned)(ix & (D_B - 1)) |
                                ((unsigned)(iy & (S_B - 1)) << 12), wb);
        int k2 = (iy >> DB_LOG) * ns + (ix >> SB_LOG);
        int p2 = atomicAdd(&cur[k2], 1);
        tuples[p2] = make_uint2((unsigned)(iy & (D_B - 1)) |
                                ((unsigned)(ix & (S_B - 1)) << 12), wb);
    }
}

// ---- K6: per-(dest bucket, src-group slice) all-LDS accumulation --------
// dynamic LDS: acc (4*D_B floats, SoA planes) + stage (S_B float4)
__global__ __launch_bounds__(SBLOCK) void k_accum(
    const uint2* __restrict__ tuples, const float4* __restrict__ charges,
    const int* __restrict__ key_base, const int* __restrict__ totals,
    float* __restrict__ partials, int n_atoms, int ns, int slices)
{
    extern __shared__ char sm[];
    float*  acc   = (float*)sm;                    // 4 planes of D_B
    float4* stage = (float4*)(sm + 4 * D_B * sizeof(float));

    int d = blockIdx.x / slices;
    int s = blockIdx.x % slices;

    for (int i = threadIdx.x; i < 4 * D_B; i += blockDim.x) acc[i] = 0.f;

    int g_lo = s * GPB;
    int g_hi = min(g_lo + GPB, ns);
    const unsigned long long* tp = (const unsigned long long*)tuples;

    for (int g = g_lo; g < g_hi; ++g) {
        __syncthreads();                       // acc zero done / prev g done
        int base_atom = g << SB_LOG;
        for (int i = threadIdx.x; i < S_B; i += blockDim.x) {
            int ga = base_atom + i;
            stage[i] = (ga < n_atoms) ? charges[ga] : make_float4(0.f, 0.f, 0.f, 0.f);
        }
        __syncthreads();

        int key = d * ns + g;
        int lo = key_base[key];
        int hi = lo + totals[key];

        int p = lo + threadIdx.x;
        for (; p + 3 * SBLOCK < hi; p += 4 * SBLOCK) {
            unsigned long long t0 = nt_u64(&tp[p]);
            unsigned long long t1 = nt_u64(&tp[p + SBLOCK]);
            unsigned long long t2 = nt_u64(&tp[p + 2 * SBLOCK]);
            unsigned long long t3 = nt_u64(&tp[p + 3 * SBLOCK]);
            unsigned u0 = (unsigned)t0, u1 = (unsigned)t1;
            unsigned u2 = (unsigned)t2, u3 = (unsigned)t3;
            float4 c0 = stage[(u0 >> 12) & (S_B - 1)];
            float4 c1 = stage[(u1 >> 12) & (S_B - 1)];
            float4 c2 = stage[(u2 >> 12) & (S_B - 1)];
            float4 c3 = stage[(u3 >> 12) & (S_B - 1)];
            float w0 = __uint_as_float((unsigned)(t0 >> 32));
            float w1 = __uint_as_float((unsigned)(t1 >> 32));
            float w2 = __uint_as_float((unsigned)(t2 >> 32));
            float w3 = __uint_as_float((unsigned)(t3 >> 32));
            int d0 = u0 & (D_B - 1), d1 = u1 & (D_B - 1);
            int d2 = u2 & (D_B - 1), d3 = u3 & (D_B - 1);
            atomicAdd(&acc[d0],             c0.x * w0);
            atomicAdd(&acc[D_B + d0],       c0.y * w0);
            atomicAdd(&acc[2 * D_B + d0],   c0.z * w0);
            atomicAdd(&acc[3 * D_B + d0],   c0.w * w0);
            atomicAdd(&acc[d1],             c1.x * w1);
            atomicAdd(&acc[D_B + d1],       c1.y * w1);
            atomicAdd(&acc[2 * D_B + d1],   c1.z * w1);
            atomicAdd(&acc[3 * D_B + d1],   c1.w * w1);
            atomicAdd(&acc[d2],             c2.x * w2);
            atomicAdd(&acc[D_B + d2],       c2.y * w2);
            atomicAdd(&acc[2 * D_B + d2],   c2.z * w2);
            atomicAdd(&acc[3 * D_B + d2],   c2.w * w2);
            atomicAdd(&acc[d3],             c3.x * w3);
            atomicAdd(&acc[D_B + d3],       c3.y * w3);
            atomicAdd(&acc[2 * D_B + d3],   c3.z * w3);
            atomicAdd(&acc[3 * D_B + d3],   c3.w * w3);
        }
        for (; p < hi; p += SBLOCK) {
            unsigned long long t = nt_u64(&tp[p]);
            unsigned u = (unsigned)t;
            float4 c = stage[(u >> 12) & (S_B - 1)];
            float w = __uint_as_float((unsigned)(t >> 32));
            int dd = u & (D_B - 1);
            atomicAdd(&acc[dd],           c.x * w);
            atomicAdd(&acc[D_B + dd],     c.y * w);
            atomicAdd(&acc[2 * D_B + dd], c.z * w);
            atomicAdd(&acc[3 * D_B + dd], c.w * w);
        }
    }
    __syncthreads();
    float* outp = partials + (size_t)blockIdx.x * (4 * D_B);
    for (int i = threadIdx.x; i < 4 * D_B; i += blockDim.x)
        nt_store(&outp[i], acc[i]);
}

// ---- K7: reduce slice partial images -> out (AoS float4) ----------------
__global__ void k_final(const float* __restrict__ partials,
                        float4* __restrict__ out, int n_atoms, int slices)
{
    int a = blockIdx.x * blockDim.x + threadIdx.x;
    if (a >= n_atoms) return;
    int d = a >> DB_LOG;
    int dl = a & (D_B - 1);
    float r0 = 0.f, r1 = 0.f, r2 = 0.f, r3 = 0.f;
    for (int s = 0; s < slices; ++s) {
        const float* p = partials + (size_t)(d * slices + s) * (4 * D_B) + dl;
        r0 += p[0];
        r1 += p[D_B];
        r2 += p[2 * D_B];
        r3 += p[3 * D_B];
    }
    out[a] = make_float4(r0, r1, r2, r3);
}

// ---- fallback (ws too small): agent-scope atomics, correct but 5 ms -----
__global__ __launch_bounds__(256) void edge_scatter_agent(
    const float4* __restrict__ charges, const int2* __restrict__ nbr,
    const float* __restrict__ dist, float* __restrict__ out, int n_edges)
{
    int e = blockIdx.x * blockDim.x + threadIdx.x;
    if (e >= n_edges) return;
    int2 ij = nbr[e];
    float w = 0.5f / dist[e];
    float4 cj = charges[ij.y];
    float4 ci = charges[ij.x];
    float* oi = out + (size_t)ij.x * 4;
    float* oj = out + (size_t)ij.y * 4;
    atomicAdd(oi + 0, cj.x * w); atomicAdd(oi + 1, cj.y * w);
    atomicAdd(oi + 2, cj.z * w); atomicAdd(oi + 3, cj.w * w);
    atomicAdd(oj + 0, ci.x * w); atomicAdd(oj + 1, ci.y * w);
    atomicAdd(oj + 2, ci.z * w); atomicAdd(oj + 3, ci.w * w);
}

extern "C" void kernel_launch(void* const* d_in, const int* in_sizes, int n_in,
                              void* d_out, int out_size, void* d_ws, size_t ws_size,
                              hipStream_t stream)
{
    // inputs: charges, cell, positions, neighbor_indices, neighbor_distances
    const float4* charges = (const float4*)d_in[0];
    const int2*   nbr     = (const int2*)d_in[3];
    const float*  dist    = (const float*)d_in[4];

    int n_edges = in_sizes[4];
    int n_atoms = out_size / 4;
    int nd = (n_atoms + D_B - 1) >> DB_LOG;    // 49
    int ns = (n_atoms + S_B - 1) >> SB_LOG;    // 49
    int nkeys = nd * ns;                        // 2401
    int slices = (ns + GPB - 1) / GPB;          // 17
    int nacc = nd * slices;                     // 833 accum blocks

    size_t n_pairs = (size_t)2 * n_edges;
    char*  w   = (char*)d_ws;
    size_t off = 0;
    auto alloc = [&](size_t bytes) -> void* {
        void* p = w + off;
        off += (bytes + 255) & ~(size_t)255;
        return p;
    };
    uint2* tuples   = (uint2*)alloc(n_pairs * sizeof(uint2));
    int*   tmp      = (int*)  alloc((size_t)NBLK_S * nkeys * sizeof(int));
    int*   offs     = (int*)  alloc((size_t)NBLK_S * nkeys * sizeof(int));
    int*   totals   = (int*)  alloc((size_t)nkeys * sizeof(int));
    int*   key_base = (int*)  alloc((size_t)nkeys * sizeof(int));
    float* partials = (float*)alloc((size_t)nacc * 4 * D_B * sizeof(float));

    size_t lds_accum = (size_t)4 * D_B * sizeof(float) + (size_t)S_B * sizeof(float4);

    if (off <= ws_size && nkeys <= KEYS_MAX) {
        k_hist   <<<NBLK_S, SBLOCK, 0, stream>>>(nbr, tmp, n_edges, nkeys, ns);
        k_rowscan<<<nkeys,  256,    0, stream>>>(tmp, offs, totals, nkeys);
        k_bases  <<<1,      1024,   0, stream>>>(totals, key_base, nkeys);
        k_addbase<<<(NBLK_S * nkeys + 511) / 512, 512, 0, stream>>>(
            offs, key_base, NBLK_S * nkeys, nkeys);
        k_scatter<<<NBLK_S, SBLOCK, 0, stream>>>(nbr, dist, offs, tuples,
                                                 n_edges, nkeys, ns);
        k_accum  <<<nacc, SBLOCK, lds_accum, stream>>>(
            tuples, charges, key_base, totals, partials, n_atoms, ns, slices);
        k_final  <<<(n_atoms + 255) / 256, 256, 0, stream>>>(
            partials, (float4*)d_out, n_atoms, slices);
    } else {
        hipMemsetAsync(d_out, 0, (size_t)out_size * sizeof(float), stream);
        edge_scatter_agent<<<(n_edges + 255) / 256, 256, 0, stream>>>(
            charges, nbr, dist, (float*)d_out, n_edges);
    }
}

// Round 7
// 1050.257 us; speedup vs baseline: 1.4465x; 1.4465x over previous
//
#include <hip/hip_runtime.h>

// 1-D bucketed counting sort + LDS accumulation (no global atomics).
// R6 falsified "gather ceiling": removing gathers didn't help. The real
// k_accum limiter (R3-R6): compiler kept ONE dependent memory chain in
// flight per wave (VGPR 16-24) -> throughput = waves x batch / latency.
// R7: batched phase machine, 16 tuples/thread/iter, fully unrolled register
// arrays, __launch_bounds__(256,4) for the VGPR budget. Phases: 16 tuple
// loads -> 16 independent charge gathers -> 64 ds_adds.

#define BLOCK   256
#define NBLK    1024       // edge chunks for hist/scatter (== rowscan width)
#define NBLK_LG 10
#define AB_LOG  10
#define A_B     1024       // atoms per bucket (16 KB LDS accumulator)
#define MAXNB   256
#define TB      16         // tuples per thread per k_accum iteration

static __device__ __forceinline__ unsigned long long nt_u64(const void* p) {
    return __builtin_nontemporal_load((const unsigned long long*)p);
}
static __device__ __forceinline__ float nt_f32(const float* p) {
    return __builtin_nontemporal_load(p);
}
static __device__ __forceinline__ void nt_store(float* p, float v) {
    __builtin_nontemporal_store(v, p);
}

// ---- K1: per-block histogram, per-wave replicas -------------------------
__global__ __launch_bounds__(BLOCK) void k_hist(
    const int2* __restrict__ nbr, int* __restrict__ blk_hist,
    int n_edges, int nb)
{
    __shared__ int h[4 * MAXNB];
    for (int i = threadIdx.x; i < 4 * MAXNB; i += blockDim.x) h[i] = 0;
    __syncthreads();
    int* hw = h + (threadIdx.x >> 6) * MAXNB;
    int per = (n_edges + gridDim.x - 1) / gridDim.x;
    int lo = blockIdx.x * per;
    int hi = min(lo + per, n_edges);
    #pragma unroll 4
    for (int e = lo + threadIdx.x; e < hi; e += blockDim.x) {
        unsigned long long v = nt_u64(&nbr[e]);
        int ix = (int)(v & 0xffffffffu);
        int iy = (int)(v >> 32);
        atomicAdd(&hw[ix >> AB_LOG], 1);
        atomicAdd(&hw[iy >> AB_LOG], 1);
    }
    __syncthreads();
    for (int i = threadIdx.x; i < nb; i += blockDim.x)
        blk_hist[i * NBLK + blockIdx.x] =
            h[i] + h[MAXNB + i] + h[2 * MAXNB + i] + h[3 * MAXNB + i];
}

// ---- K2: exclusive scan of each bucket's row (NBLK entries) -------------
__global__ __launch_bounds__(NBLK) void k_rowscan(
    const int* __restrict__ blk_hist, int* __restrict__ offs,
    int* __restrict__ totals)
{
    __shared__ int a[NBLK];
    int b = blockIdx.x, t = threadIdx.x;
    int v = blk_hist[b * NBLK + t];
    a[t] = v;
    __syncthreads();
    for (int off = 1; off < NBLK; off <<= 1) {
        int x = (t >= off) ? a[t - off] : 0;
        __syncthreads();
        a[t] += x;
        __syncthreads();
    }
    offs[b * NBLK + t] = a[t] - v;       // exclusive within bucket
    if (t == NBLK - 1) totals[b] = a[t];
}

// ---- K3: bucket bases (parallel LDS scan, one block) --------------------
__global__ __launch_bounds__(MAXNB) void k_bases(
    const int* __restrict__ totals, int* __restrict__ bases, int nb)
{
    __shared__ int a[MAXNB];
    int t = threadIdx.x;
    int v = (t < nb) ? totals[t] : 0;
    a[t] = v;
    __syncthreads();
    for (int off = 1; off < MAXNB; off <<= 1) {
        int x = (t >= off) ? a[t - off] : 0;
        __syncthreads();
        a[t] += x;
        __syncthreads();
    }
    if (t < nb) bases[t] = a[t] - v;
}

// ---- K4: offs[i] += bases[i / NBLK] -------------------------------------
__global__ void k_addbase(int* __restrict__ offs, const int* __restrict__ bases, int n)
{
    int i = blockIdx.x * blockDim.x + threadIdx.x;
    if (i < n) offs[i] += bases[i >> NBLK_LG];
}

// ---- K5: counting-sort scatter of tuples --------------------------------
__global__ __launch_bounds__(BLOCK) void k_scatter(
    const int2* __restrict__ nbr, const float* __restrict__ dist,
    const int* __restrict__ offs, uint2* __restrict__ tuples,
    int n_edges, int nb)
{
    __shared__ int cur[MAXNB];
    for (int i = threadIdx.x; i < nb; i += blockDim.x)
        cur[i] = offs[i * NBLK + blockIdx.x];
    __syncthreads();
    int per = (n_edges + gridDim.x - 1) / gridDim.x;
    int lo = blockIdx.x * per;
    int hi = min(lo + per, n_edges);
    #pragma unroll 4
    for (int e = lo + threadIdx.x; e < hi; e += blockDim.x) {
        unsigned long long v = nt_u64(&nbr[e]);
        int ix = (int)(v & 0xffffffffu);
        int iy = (int)(v >> 32);
        float w = 0.5f / nt_f32(&dist[e]);
        unsigned wb = __float_as_uint(w);
        int pi = atomicAdd(&cur[ix >> AB_LOG], 1);
        tuples[pi] = make_uint2((unsigned)(ix & (A_B - 1)) | ((unsigned)iy << AB_LOG), wb);
        int pj = atomicAdd(&cur[iy >> AB_LOG], 1);
        tuples[pj] = make_uint2((unsigned)(iy & (A_B - 1)) | ((unsigned)ix << AB_LOG), wb);
    }
}

// ---- K6: per-(bucket,slice) LDS accumulation, 16-wide batch -------------
__global__ __launch_bounds__(BLOCK, 4) void k_accum(
    const uint2* __restrict__ tuples, const float4* __restrict__ charges,
    const int* __restrict__ bases, const int* __restrict__ totals,
    float* __restrict__ partials, int nslice)
{
    __shared__ float acc[4 * A_B];     // 16 KB, SoA: [channel][atom]
    int b = blockIdx.x / nslice;
    int s = blockIdx.x % nslice;
    for (int i = threadIdx.x; i < 4 * A_B; i += blockDim.x) acc[i] = 0.f;
    __syncthreads();
    int start = bases[b], cnt = totals[b];
    int lo = start + (int)((long long)cnt * s / nslice);
    int hi = start + (int)((long long)cnt * (s + 1) / nslice);

    const unsigned long long* tp = (const unsigned long long*)tuples;

    int p = lo + threadIdx.x;
    // main: 16 tuples per thread per iteration, three phases
    for (; p + (TB - 1) * BLOCK < hi; p += TB * BLOCK) {
        unsigned long long t[TB];
        #pragma unroll
        for (int k = 0; k < TB; ++k)
            t[k] = nt_u64(&tp[p + k * BLOCK]);          // 16 loads in flight

        float4 c[TB];
        #pragma unroll
        for (int k = 0; k < TB; ++k)
            c[k] = charges[((unsigned)t[k]) >> AB_LOG]; // 16 gathers in flight

        #pragma unroll
        for (int k = 0; k < TB; ++k) {
            unsigned u = (unsigned)t[k];
            float w = __uint_as_float((unsigned)(t[k] >> 32));
            int d = u & (A_B - 1);
            atomicAdd(&acc[d],             c[k].x * w);
            atomicAdd(&acc[A_B + d],       c[k].y * w);
            atomicAdd(&acc[2 * A_B + d],   c[k].z * w);
            atomicAdd(&acc[3 * A_B + d],   c[k].w * w);
        }
    }
    // tail
    for (; p < hi; p += BLOCK) {
        unsigned long long t = nt_u64(&tp[p]);
        unsigned u = (unsigned)t;
        float4 c = charges[u >> AB_LOG];
        float w = __uint_as_float((unsigned)(t >> 32));
        int d = u & (A_B - 1);
        atomicAdd(&acc[d],           c.x * w);
        atomicAdd(&acc[A_B + d],     c.y * w);
        atomicAdd(&acc[2 * A_B + d], c.z * w);
        atomicAdd(&acc[3 * A_B + d], c.w * w);
    }
    __syncthreads();
    float* outp = partials + (size_t)blockIdx.x * (4 * A_B);
    for (int i = threadIdx.x; i < 4 * A_B; i += blockDim.x)
        nt_store(&outp[i], acc[i]);
}

// ---- K7: reduce nslice SoA partial images -> out (AoS float4) -----------
__global__ void k_final(const float* __restrict__ partials,
                        float4* __restrict__ out, int n_atoms, int nslice)
{
    int a = blockIdx.x * blockDim.x + threadIdx.x;
    if (a >= n_atoms) return;
    int b = a >> AB_LOG;
    int local = a & (A_B - 1);
    const float* base = partials + (size_t)(b * nslice) * (4 * A_B) + local;
    float r0 = 0.f, r1 = 0.f, r2 = 0.f, r3 = 0.f;
    for (int s = 0; s < nslice; ++s) {
        const float* p = base + (size_t)s * (4 * A_B);
        r0 += p[0];
        r1 += p[A_B];
        r2 += p[2 * A_B];
        r3 += p[3 * A_B];
    }
    out[a] = make_float4(r0, r1, r2, r3);
}

// ---- fallback (ws too small): agent-scope atomics, correct but 5 ms -----
__global__ __launch_bounds__(BLOCK) void edge_scatter_agent(
    const float4* __restrict__ charges, const int2* __restrict__ nbr,
    const float* __restrict__ dist, float* __restrict__ out, int n_edges)
{
    int e = blockIdx.x * blockDim.x + threadIdx.x;
    if (e >= n_edges) return;
    int2 ij = nbr[e];
    float w = 0.5f / dist[e];
    float4 cj = charges[ij.y];
    float4 ci = charges[ij.x];
    float* oi = out + (size_t)ij.x * 4;
    float* oj = out + (size_t)ij.y * 4;
    atomicAdd(oi + 0, cj.x * w); atomicAdd(oi + 1, cj.y * w);
    atomicAdd(oi + 2, cj.z * w); atomicAdd(oi + 3, cj.w * w);
    atomicAdd(oj + 0, ci.x * w); atomicAdd(oj + 1, ci.y * w);
    atomicAdd(oj + 2, ci.z * w); atomicAdd(oj + 3, ci.w * w);
}

extern "C" void kernel_launch(void* const* d_in, const int* in_sizes, int n_in,
                              void* d_out, int out_size, void* d_ws, size_t ws_size,
                              hipStream_t stream)
{
    // inputs: charges, cell, positions, neighbor_indices, neighbor_distances
    const float4* charges = (const float4*)d_in[0];
    const int2*   nbr     = (const int2*)d_in[3];
    const float*  dist    = (const float*)d_in[4];

    int n_edges = in_sizes[4];
    int n_atoms = out_size / 4;
    int nb = (n_atoms + A_B - 1) >> AB_LOG;     // 196 for 200000 atoms

    size_t n_pairs = (size_t)2 * n_edges;
    char*  w   = (char*)d_ws;
    size_t off = 0;
    auto alloc = [&](size_t bytes) -> void* {
        void* p = w + off;
        off += (bytes + 255) & ~(size_t)255;
        return p;
    };
    uint2* tuples   = (uint2*)alloc(n_pairs * sizeof(uint2));
    int*   blk_hist = (int*)  alloc((size_t)nb * NBLK * sizeof(int));
    int*   offs     = (int*)  alloc((size_t)nb * NBLK * sizeof(int));
    int*   totals   = (int*)  alloc((size_t)nb * sizeof(int));
    int*   bases    = (int*)  alloc((size_t)nb * sizeof(int));

    // adaptive slice count: partials = nb*nslice*A_B*4*4 bytes
    size_t slice_bytes = (size_t)nb * A_B * 4 * sizeof(float);
    int nslice = 16;
    while (nslice > 1 && off + (size_t)nslice * slice_bytes > ws_size) nslice >>= 1;
    float* partials = (float*)alloc((size_t)nslice * slice_bytes);

    if (off <= ws_size && nb <= MAXNB) {
        k_hist   <<<NBLK, BLOCK, 0, stream>>>(nbr, blk_hist, n_edges, nb);
        k_rowscan<<<nb,   NBLK,  0, stream>>>(blk_hist, offs, totals);
        k_bases  <<<1,    MAXNB, 0, stream>>>(totals, bases, nb);
        k_addbase<<<(nb * NBLK + 255) / 256, 256, 0, stream>>>(offs, bases, nb * NBLK);
        k_scatter<<<NBLK, BLOCK, 0, stream>>>(nbr, dist, offs, tuples, n_edges, nb);
        k_accum  <<<nb * nslice, BLOCK, 0, stream>>>(tuples, charges, bases, totals,
                                                     partials, nslice);
        k_final  <<<(n_atoms + 255) / 256, 256, 0, stream>>>(
            partials, (float4*)d_out, n_atoms, nslice);
    } else {
        hipMemsetAsync(d_out, 0, (size_t)out_size * sizeof(float), stream);
        edge_scatter_agent<<<(n_edges + BLOCK - 1) / BLOCK, BLOCK, 0, stream>>>(
            charges, nbr, dist, (float*)d_out, n_edges);
    }
}